// Round 5
// baseline (270.322 us; speedup 1.0000x reference)
//
#include <hip/hip_runtime.h>

typedef short short8 __attribute__((ext_vector_type(8)));
typedef float f32x4 __attribute__((ext_vector_type(4)));
typedef unsigned short u16x4 __attribute__((ext_vector_type(4)));

#define DEV static __device__ __forceinline__

DEV float b2f(unsigned short u) { return __uint_as_float(((unsigned)u) << 16); }
DEV unsigned short f2b(float f) {
    unsigned u = __float_as_uint(f);
    u += 0x7FFFu + ((u >> 16) & 1u);
    return (unsigned short)(u >> 16);
}
DEV float wred_sum(float v) {
#pragma unroll
    for (int o = 32; o; o >>= 1) v += __shfl_xor(v, o);
    return v;
}

DEV void gld_lds16(const unsigned short* g, unsigned short* l) {
    __builtin_amdgcn_global_load_lds((const __attribute__((address_space(1))) void*)g,
                                     (__attribute__((address_space(3))) void*)l, 16, 0, 0);
}

// ---------------- LayerNorm ----------------
template <bool OUT_BF16>
__global__ __launch_bounds__(256) void ln_kernel(const float* __restrict__ in,
                                                 void* __restrict__ out_v,
                                                 const float* __restrict__ alpha_p,
                                                 const float* __restrict__ bias_p) {
    __shared__ float redA[4], redB[4];
    const int row = blockIdx.x;
    const int t = threadIdx.x;
    const int lane = t & 63, w = t >> 6;

    f32x4 xv = *(const f32x4*)&in[(size_t)row * 1024 + t * 4];

    float s = wred_sum(xv[0] + xv[1] + xv[2] + xv[3]);
    if (lane == 0) redA[w] = s;
    __syncthreads();
    float mean = (redA[0] + redA[1] + redA[2] + redA[3]) * (1.0f / 1024.0f);

    float d0 = xv[0] - mean, d1 = xv[1] - mean, d2 = xv[2] - mean, d3 = xv[3] - mean;
    float ss = wred_sum(d0 * d0 + d1 * d1 + d2 * d2 + d3 * d3);
    if (lane == 0) redB[w] = ss;
    __syncthreads();
    float var = (redB[0] + redB[1] + redB[2] + redB[3]) * (1.0f / 1023.0f);
    float denom = sqrtf(var) + 1e-9f;
    float inv = alpha_p[0] / denom;
    float bias = bias_p[0];

    if (OUT_BF16) {
        u16x4 o;
        o[0] = f2b(d0 * inv + bias);
        o[1] = f2b(d1 * inv + bias);
        o[2] = f2b(d2 * inv + bias);
        o[3] = f2b(d3 * inv + bias);
        *(u16x4*)&((unsigned short*)out_v)[(size_t)row * 1024 + t * 4] = o;
    } else {
        f32x4 o;
        o[0] = d0 * inv + bias;
        o[1] = d1 * inv + bias;
        o[2] = d2 * inv + bias;
        o[3] = d3 * inv + bias;
        *(f32x4*)&((float*)out_v)[(size_t)row * 1024 + t * 4] = o;
    }
}

// ---------------- f32 -> bf16 transpose ----------------
__global__ __launch_bounds__(256) void transpose_cast_kernel(const float* __restrict__ in,
                                                             unsigned short* __restrict__ out,
                                                             int R, int C) {
    __shared__ unsigned short tile[32][33];
    const int c0 = blockIdx.x * 32, r0 = blockIdx.y * 32;
    const int x = threadIdx.x, y0 = threadIdx.y;
#pragma unroll
    for (int yy = y0; yy < 32; yy += 8) tile[yy][x] = f2b(in[(size_t)(r0 + yy) * C + c0 + x]);
    __syncthreads();
#pragma unroll
    for (int yy = y0; yy < 32; yy += 8) out[(size_t)(c0 + yy) * R + r0 + x] = tile[x][yy];
}

// ---------------- bf16 [b][s][d] -> [b][d][s] transpose ----------------
__global__ __launch_bounds__(256) void transpose_bf16_batch(const unsigned short* __restrict__ in,
                                                            unsigned short* __restrict__ out) {
    __shared__ unsigned short tile[32][33];
    const int b = blockIdx.z;
    const int d0 = blockIdx.x * 32, s0 = blockIdx.y * 32;
    const unsigned short* I = in + (size_t)b * 1024 * 1024;
    unsigned short* O = out + (size_t)b * 1024 * 1024;
    const int x = threadIdx.x, y0 = threadIdx.y;
#pragma unroll
    for (int yy = y0; yy < 32; yy += 8) tile[yy][x] = I[(size_t)(s0 + yy) * 1024 + d0 + x];
    __syncthreads();
#pragma unroll
    for (int yy = y0; yy < 32; yy += 8) O[(size_t)(d0 + yy) * 1024 + s0 + x] = tile[x][yy];
}

// ---------------- GEMM v2: global_load_lds staging, BK=64, both-sides XOR swizzle ----------------
template <int BM, int BN, bool RELU, bool RES, bool OUT_BF16>
__global__ __launch_bounds__(256) void gemm2(const unsigned short* __restrict__ A,
                                             const unsigned short* __restrict__ Bt,
                                             const float* __restrict__ bias,
                                             const float* __restrict__ res,
                                             void* __restrict__ C_v,
                                             int M, int N, int K) {
    constexpr int WM = BM / 2, WN = BN / 2;
    constexpr int FM = WM / 16, FN = WN / 16;
    __shared__ __align__(16) unsigned short As[BM * 64];
    __shared__ __align__(16) unsigned short Bs[BN * 64];

    const int t = threadIdx.x;
    const int lane = t & 63, w = t >> 6;
    const int wr = w >> 1, wc = w & 1;
    const int lr = lane & 15, g = lane >> 4;

    const int nwg = gridDim.x;
    const int cpx = nwg >> 3;
    const int wg = blockIdx.x;
    const int swz = (wg & 7) * cpx + (wg >> 3);
    const int NB = N / BN;
    const int m0 = (swz / NB) * BM, n0 = (swz % NB) * BN;

    f32x4 acc[FM][FN];
#pragma unroll
    for (int i = 0; i < FM; ++i)
#pragma unroll
        for (int j = 0; j < FN; ++j) acc[i][j] = (f32x4)0.0f;

    for (int k0 = 0; k0 < K; k0 += 64) {
        __syncthreads();
#pragma unroll
        for (int i = 0; i < BM / 32; ++i) {
            int id = i * 256 + t;
            int row = id >> 3, ch = id & 7;
            gld_lds16(&A[(size_t)(m0 + row) * K + k0 + ((ch ^ (row & 7)) * 8)],
                      &As[(size_t)(i * 256 + (t & ~63)) * 8]);
        }
#pragma unroll
        for (int i = 0; i < BN / 32; ++i) {
            int id = i * 256 + t;
            int row = id >> 3, ch = id & 7;
            gld_lds16(&Bt[(size_t)(n0 + row) * K + k0 + ((ch ^ (row & 7)) * 8)],
                      &Bs[(size_t)(i * 256 + (t & ~63)) * 8]);
        }
        __syncthreads();

        short8 af[FM][2], bfr[FN][2];
#pragma unroll
        for (int mi = 0; mi < FM; ++mi) {
            int row = wr * WM + mi * 16 + lr;
#pragma unroll
            for (int ks = 0; ks < 2; ++ks) {
                int ch = (ks * 4 + g) ^ (row & 7);
                af[mi][ks] = *(const short8*)&As[row * 64 + ch * 8];
            }
        }
#pragma unroll
        for (int ni = 0; ni < FN; ++ni) {
            int row = wc * WN + ni * 16 + lr;
#pragma unroll
            for (int ks = 0; ks < 2; ++ks) {
                int ch = (ks * 4 + g) ^ (row & 7);
                bfr[ni][ks] = *(const short8*)&Bs[row * 64 + ch * 8];
            }
        }
#pragma unroll
        for (int ks = 0; ks < 2; ++ks)
#pragma unroll
            for (int mi = 0; mi < FM; ++mi)
#pragma unroll
                for (int ni = 0; ni < FN; ++ni)
                    acc[mi][ni] = __builtin_amdgcn_mfma_f32_16x16x32_bf16(af[mi][ks], bfr[ni][ks], acc[mi][ni], 0, 0, 0);
    }

    const int lg = g;
#pragma unroll
    for (int ni = 0; ni < FN; ++ni) {
        int col = n0 + wc * WN + ni * 16 + lr;
        float bv = bias[col];
#pragma unroll
        for (int mi = 0; mi < FM; ++mi) {
            int row0 = m0 + wr * WM + mi * 16 + lg * 4;
#pragma unroll
            for (int i = 0; i < 4; ++i) {
                int row = row0 + i;
                float x = acc[mi][ni][i] + bv;
                if (RES) x += res[(size_t)row * N + col];
                if (RELU) x = fmaxf(x, 0.0f);
                if (OUT_BF16)
                    ((unsigned short*)C_v)[(size_t)row * N + col] = f2b(x);
                else
                    ((float*)C_v)[(size_t)row * N + col] = x;
            }
        }
    }
}

// ---------------- MFMA flash attention v2 ----------------
// grid (bh=64, qblk=16) -> all 16 q-sibling blocks of a head share an XCD (id%8 = bh%8).
// Double-buffered K/V via global_load_lds (pre-swizzled source), prefetch-before-compute;
// defer-max softmax (THR=8), setprio around MFMA clusters.
__global__ __launch_bounds__(256) void attn_mfma2(const unsigned short* __restrict__ p,
                                                  const unsigned short* __restrict__ pT,
                                                  unsigned short* __restrict__ out) {
    __shared__ __align__(16) unsigned short Ks[2][64 * 64];
    __shared__ __align__(16) unsigned short Vt[2][64 * 64];
    __shared__ __align__(16) unsigned short Ps[4 * 16 * 64];

    const int t = threadIdx.x;
    const int lane = t & 63, w = t >> 6;
    const int lr = lane & 15, g = lane >> 4;
    const int bh = blockIdx.x;     // 0..63
    const int qblk = blockIdx.y;   // 0..15
    const int b = bh >> 4, h = bh & 15;

    const unsigned short* Pm = p + (size_t)b * (1024 * 1024) + h * 64;
    const unsigned short* PT = pT + (size_t)b * (1024 * 1024) + (size_t)(h * 64) * 1024;

    const int q0 = qblk * 64 + w * 16;
    short8 qa0 = *(const short8*)&Pm[(size_t)(q0 + lr) * 1024 + g * 8];
    short8 qa1 = *(const short8*)&Pm[(size_t)(q0 + lr) * 1024 + 32 + g * 8];

    f32x4 acc[4];
#pragma unroll
    for (int i = 0; i < 4; ++i) acc[i] = (f32x4)0.0f;
    float mrow[4] = {-1e30f, -1e30f, -1e30f, -1e30f};
    float lsum[4] = {0.f, 0.f, 0.f, 0.f};

    unsigned short* Pw = &Ps[w * 16 * 64];

    // async stage of tile kt into buffer buf: K rows (p) + V^T rows (pT), source pre-swizzled
#define STAGE(buf, kt)                                                                     \
    {                                                                                      \
        const int key0 = (kt) * 64;                                                        \
        _Pragma("unroll") for (int i = 0; i < 2; ++i) {                                    \
            int id = i * 256 + t;                                                          \
            int row = id >> 3, ch = id & 7;                                                \
            gld_lds16(&Pm[(size_t)(key0 + row) * 1024 + ((ch ^ (row & 7)) * 8)],           \
                      &Ks[buf][(size_t)(i * 256 + (t & ~63)) * 8]);                        \
            gld_lds16(&PT[(size_t)row * 1024 + key0 + ((ch ^ (row & 7)) * 8)],             \
                      &Vt[buf][(size_t)(i * 256 + (t & ~63)) * 8]);                        \
        }                                                                                  \
    }

    STAGE(0, 0);
    __syncthreads();
    int cur = 0;

    for (int kt = 0; kt < 16; ++kt) {
        if (kt < 15) STAGE(cur ^ 1, kt + 1);  // async prefetch; drains at end-of-iter barrier

        // QK^T
        f32x4 s_acc[4];
        __builtin_amdgcn_s_setprio(1);
#pragma unroll
        for (int kg = 0; kg < 4; ++kg) {
            s_acc[kg] = (f32x4)0.0f;
            int krow = kg * 16 + lr;
            int swz = (krow & 7) << 3;
            short8 kb0 = *(const short8*)&Ks[cur][krow * 64 + ((g * 8) ^ swz)];
            short8 kb1 = *(const short8*)&Ks[cur][krow * 64 + ((32 + g * 8) ^ swz)];
            s_acc[kg] = __builtin_amdgcn_mfma_f32_16x16x32_bf16(qa0, kb0, s_acc[kg], 0, 0, 0);
            s_acc[kg] = __builtin_amdgcn_mfma_f32_16x16x32_bf16(qa1, kb1, s_acc[kg], 0, 0, 0);
        }
        __builtin_amdgcn_s_setprio(0);

        // tile max per row (row q=g*4+reg spans 16 lanes of same g)
        float mx[4];
#pragma unroll
        for (int reg = 0; reg < 4; ++reg) {
            float m = fmaxf(fmaxf(s_acc[0][reg], s_acc[1][reg]),
                            fmaxf(s_acc[2][reg], s_acc[3][reg])) * 0.125f;
            m = fmaxf(m, __shfl_xor(m, 1));
            m = fmaxf(m, __shfl_xor(m, 2));
            m = fmaxf(m, __shfl_xor(m, 4));
            m = fmaxf(m, __shfl_xor(m, 8));
            mx[reg] = m;
        }
        // defer-max (T13): skip O-rescale when growth <= 8 for all rows in wave
        bool small = (mx[0] <= mrow[0] + 8.f) && (mx[1] <= mrow[1] + 8.f) &&
                     (mx[2] <= mrow[2] + 8.f) && (mx[3] <= mrow[3] + 8.f);
        if (__all(small)) {
#pragma unroll
            for (int reg = 0; reg < 4; ++reg) {
                float psum = 0.f;
#pragma unroll
                for (int kg = 0; kg < 4; ++kg) {
                    float pv = __expf(s_acc[kg][reg] * 0.125f - mrow[reg]);
                    s_acc[kg][reg] = pv;
                    psum += pv;
                }
                psum += __shfl_xor(psum, 1);
                psum += __shfl_xor(psum, 2);
                psum += __shfl_xor(psum, 4);
                psum += __shfl_xor(psum, 8);
                lsum[reg] += psum;
            }
        } else {
#pragma unroll
            for (int reg = 0; reg < 4; ++reg) {
                float mnew = fmaxf(mrow[reg], mx[reg]);
                float scale = __expf(mrow[reg] - mnew);
                mrow[reg] = mnew;
                float psum = 0.f;
#pragma unroll
                for (int kg = 0; kg < 4; ++kg) {
                    float pv = __expf(s_acc[kg][reg] * 0.125f - mnew);
                    s_acc[kg][reg] = pv;
                    psum += pv;
                }
                psum += __shfl_xor(psum, 1);
                psum += __shfl_xor(psum, 2);
                psum += __shfl_xor(psum, 4);
                psum += __shfl_xor(psum, 8);
                lsum[reg] = lsum[reg] * scale + psum;
#pragma unroll
                for (int dg = 0; dg < 4; ++dg) acc[dg][reg] *= scale;
            }
        }

        // P (C-layout) -> per-wave LDS -> A-frag layout
#pragma unroll
        for (int reg = 0; reg < 4; ++reg) {
            int q = g * 4 + reg;
            int swz = (q & 7) << 3;
#pragma unroll
            for (int kg = 0; kg < 4; ++kg) {
                int key = lr + 16 * kg;
                Pw[q * 64 + (key ^ swz)] = f2b(s_acc[kg][reg]);
            }
        }
        int pswz = (lr & 7) << 3;
        short8 pa0 = *(const short8*)&Pw[lr * 64 + ((g * 8) ^ pswz)];
        short8 pa1 = *(const short8*)&Pw[lr * 64 + ((32 + g * 8) ^ pswz)];

        // PV
        __builtin_amdgcn_s_setprio(1);
#pragma unroll
        for (int dg = 0; dg < 4; ++dg) {
            int drow = dg * 16 + lr;
            int swz = (drow & 7) << 3;
            short8 vb0 = *(const short8*)&Vt[cur][drow * 64 + ((g * 8) ^ swz)];
            short8 vb1 = *(const short8*)&Vt[cur][drow * 64 + ((32 + g * 8) ^ swz)];
            acc[dg] = __builtin_amdgcn_mfma_f32_16x16x32_bf16(pa0, vb0, acc[dg], 0, 0, 0);
            acc[dg] = __builtin_amdgcn_mfma_f32_16x16x32_bf16(pa1, vb1, acc[dg], 0, 0, 0);
        }
        __builtin_amdgcn_s_setprio(0);

        __syncthreads();  // drains prefetch vmcnt + guards LDS buffer flip
        cur ^= 1;
    }
#undef STAGE

    unsigned short* O = out + (size_t)b * (1024 * 1024) + h * 64;
#pragma unroll
    for (int reg = 0; reg < 4; ++reg) {
        float inv = 1.0f / lsum[reg];
        int q = q0 + g * 4 + reg;
#pragma unroll
        for (int dg = 0; dg < 4; ++dg) {
            O[(size_t)q * 1024 + dg * 16 + lr] = f2b(acc[dg][reg] * inv);
        }
    }
}

// ---------------- launch ----------------
extern "C" void kernel_launch(void* const* d_in, const int* in_sizes, int n_in,
                              void* d_out, int out_size, void* d_ws, size_t ws_size,
                              hipStream_t stream) {
    const float* x = (const float*)d_in[0];
    const float* wq_w = (const float*)d_in[1];
    const float* wq_b = (const float*)d_in[2];
    const float* wo_w = (const float*)d_in[3];
    const float* wo_b = (const float*)d_in[4];
    const float* ff1_w = (const float*)d_in[5];
    const float* ff1_b = (const float*)d_in[6];
    const float* ff2_w = (const float*)d_in[7];
    const float* ff2_b = (const float*)d_in[8];
    const float* alpha1 = (const float*)d_in[9];
    const float* bias1 = (const float*)d_in[10];
    const float* alpha2 = (const float*)d_in[11];
    const float* bias2 = (const float*)d_in[12];
    const float* alpha3 = (const float*)d_in[13];
    const float* bias3 = (const float*)d_in[14];
    float* out = (float*)d_out;

    const size_t MB = 1u << 20;
    char* ws = (char*)d_ws;
    unsigned short* wq_t = (unsigned short*)(ws + 0 * MB);
    unsigned short* wo_t = (unsigned short*)(ws + 2 * MB);
    unsigned short* ff1_t = (unsigned short*)(ws + 4 * MB);
    unsigned short* ff2_t = (unsigned short*)(ws + 12 * MB);
    unsigned short* lnbuf = (unsigned short*)(ws + 20 * MB);
    unsigned short* pbuf = (unsigned short*)(ws + 28 * MB);
    unsigned short* attn = (unsigned short*)(ws + 36 * MB);
    float* h1 = (float*)(ws + 44 * MB);
    unsigned short* pbT = (unsigned short*)(ws + 60 * MB);
    unsigned short* mid = (unsigned short*)(ws + 60 * MB);
    float* h2 = (float*)(ws + 28 * MB);

    const int M = 4096;

    transpose_cast_kernel<<<dim3(32, 32), dim3(32, 8), 0, stream>>>(wq_w, wq_t, 1024, 1024);
    transpose_cast_kernel<<<dim3(32, 32), dim3(32, 8), 0, stream>>>(wo_w, wo_t, 1024, 1024);
    transpose_cast_kernel<<<dim3(128, 32), dim3(32, 8), 0, stream>>>(ff1_w, ff1_t, 1024, 4096);
    transpose_cast_kernel<<<dim3(32, 128), dim3(32, 8), 0, stream>>>(ff2_w, ff2_t, 4096, 1024);

    ln_kernel<true><<<M, 256, 0, stream>>>(x, lnbuf, alpha1, bias1);
    gemm2<128, 64, false, false, true><<<512, 256, 0, stream>>>(lnbuf, wq_t, wq_b, nullptr, pbuf, M, 1024, 1024);
    transpose_bf16_batch<<<dim3(32, 32, 4), dim3(32, 8), 0, stream>>>(pbuf, pbT);
    attn_mfma2<<<dim3(64, 16), 256, 0, stream>>>(pbuf, pbT, attn);
    gemm2<128, 64, false, true, false><<<512, 256, 0, stream>>>(attn, wo_t, wo_b, x, h1, M, 1024, 1024);
    ln_kernel<true><<<M, 256, 0, stream>>>(h1, lnbuf, alpha2, bias2);
    gemm2<128, 128, true, false, true><<<1024, 256, 0, stream>>>(lnbuf, ff1_t, ff1_b, nullptr, mid, M, 4096, 1024);
    gemm2<128, 64, false, true, false><<<512, 256, 0, stream>>>(mid, ff2_t, ff2_b, h1, h2, M, 1024, 4096);
    ln_kernel<false><<<M, 256, 0, stream>>>(h2, out, alpha3, bias3);
}

// Round 6
// 262.997 us; speedup vs baseline: 1.0279x; 1.0279x over previous
//
#include <hip/hip_runtime.h>

typedef short short8 __attribute__((ext_vector_type(8)));
typedef float f32x4 __attribute__((ext_vector_type(4)));
typedef unsigned short u16x4 __attribute__((ext_vector_type(4)));

#define DEV static __device__ __forceinline__

DEV float b2f(unsigned short u) { return __uint_as_float(((unsigned)u) << 16); }
DEV unsigned short f2b(float f) {
    unsigned u = __float_as_uint(f);
    u += 0x7FFFu + ((u >> 16) & 1u);
    return (unsigned short)(u >> 16);
}
DEV float wred_sum(float v) {
#pragma unroll
    for (int o = 32; o; o >>= 1) v += __shfl_xor(v, o);
    return v;
}
DEV float fast_exp2(float x) {
#if __has_builtin(__builtin_amdgcn_exp2f)
    return __builtin_amdgcn_exp2f(x);
#else
    return exp2f(x);
#endif
}

DEV void gld_lds16(const unsigned short* g, unsigned short* l) {
    __builtin_amdgcn_global_load_lds((const __attribute__((address_space(1))) void*)g,
                                     (__attribute__((address_space(3))) void*)l, 16, 0, 0);
}

// ---------------- LayerNorm ----------------
template <bool OUT_BF16>
__global__ __launch_bounds__(256) void ln_kernel(const float* __restrict__ in,
                                                 void* __restrict__ out_v,
                                                 const float* __restrict__ alpha_p,
                                                 const float* __restrict__ bias_p) {
    __shared__ float redA[4], redB[4];
    const int row = blockIdx.x;
    const int t = threadIdx.x;
    const int lane = t & 63, w = t >> 6;

    f32x4 xv = *(const f32x4*)&in[(size_t)row * 1024 + t * 4];

    float s = wred_sum(xv[0] + xv[1] + xv[2] + xv[3]);
    if (lane == 0) redA[w] = s;
    __syncthreads();
    float mean = (redA[0] + redA[1] + redA[2] + redA[3]) * (1.0f / 1024.0f);

    float d0 = xv[0] - mean, d1 = xv[1] - mean, d2 = xv[2] - mean, d3 = xv[3] - mean;
    float ss = wred_sum(d0 * d0 + d1 * d1 + d2 * d2 + d3 * d3);
    if (lane == 0) redB[w] = ss;
    __syncthreads();
    float var = (redB[0] + redB[1] + redB[2] + redB[3]) * (1.0f / 1023.0f);
    float denom = sqrtf(var) + 1e-9f;
    float inv = alpha_p[0] / denom;
    float bias = bias_p[0];

    if (OUT_BF16) {
        u16x4 o;
        o[0] = f2b(d0 * inv + bias);
        o[1] = f2b(d1 * inv + bias);
        o[2] = f2b(d2 * inv + bias);
        o[3] = f2b(d3 * inv + bias);
        *(u16x4*)&((unsigned short*)out_v)[(size_t)row * 1024 + t * 4] = o;
    } else {
        f32x4 o;
        o[0] = d0 * inv + bias;
        o[1] = d1 * inv + bias;
        o[2] = d2 * inv + bias;
        o[3] = d3 * inv + bias;
        *(f32x4*)&((float*)out_v)[(size_t)row * 1024 + t * 4] = o;
    }
}

// ---------------- f32 -> bf16 transpose ----------------
__global__ __launch_bounds__(256) void transpose_cast_kernel(const float* __restrict__ in,
                                                             unsigned short* __restrict__ out,
                                                             int R, int C) {
    __shared__ unsigned short tile[32][33];
    const int c0 = blockIdx.x * 32, r0 = blockIdx.y * 32;
    const int x = threadIdx.x, y0 = threadIdx.y;
#pragma unroll
    for (int yy = y0; yy < 32; yy += 8) tile[yy][x] = f2b(in[(size_t)(r0 + yy) * C + c0 + x]);
    __syncthreads();
#pragma unroll
    for (int yy = y0; yy < 32; yy += 8) out[(size_t)(c0 + yy) * R + r0 + x] = tile[x][yy];
}

// ---------------- bf16 [b][s][d] -> [b][d][s] transpose ----------------
__global__ __launch_bounds__(256) void transpose_bf16_batch(const unsigned short* __restrict__ in,
                                                            unsigned short* __restrict__ out) {
    __shared__ unsigned short tile[32][33];
    const int b = blockIdx.z;
    const int d0 = blockIdx.x * 32, s0 = blockIdx.y * 32;
    const unsigned short* I = in + (size_t)b * 1024 * 1024;
    unsigned short* O = out + (size_t)b * 1024 * 1024;
    const int x = threadIdx.x, y0 = threadIdx.y;
#pragma unroll
    for (int yy = y0; yy < 32; yy += 8) tile[yy][x] = I[(size_t)(s0 + yy) * 1024 + d0 + x];
    __syncthreads();
#pragma unroll
    for (int yy = y0; yy < 32; yy += 8) O[(size_t)(d0 + yy) * 1024 + s0 + x] = tile[x][yy];
}

// ---------------- GEMM v2: global_load_lds staging, BK=64, both-sides XOR swizzle ----------------
template <int BM, int BN, bool RELU, bool RES, bool OUT_BF16>
__global__ __launch_bounds__(256) void gemm2(const unsigned short* __restrict__ A,
                                             const unsigned short* __restrict__ Bt,
                                             const float* __restrict__ bias,
                                             const float* __restrict__ res,
                                             void* __restrict__ C_v,
                                             int M, int N, int K) {
    constexpr int WM = BM / 2, WN = BN / 2;
    constexpr int FM = WM / 16, FN = WN / 16;
    __shared__ __align__(16) unsigned short As[BM * 64];
    __shared__ __align__(16) unsigned short Bs[BN * 64];

    const int t = threadIdx.x;
    const int lane = t & 63, w = t >> 6;
    const int wr = w >> 1, wc = w & 1;
    const int lr = lane & 15, g = lane >> 4;

    const int nwg = gridDim.x;
    const int cpx = nwg >> 3;
    const int wg = blockIdx.x;
    const int swz = (wg & 7) * cpx + (wg >> 3);
    const int NB = N / BN;
    const int m0 = (swz / NB) * BM, n0 = (swz % NB) * BN;

    f32x4 acc[FM][FN];
#pragma unroll
    for (int i = 0; i < FM; ++i)
#pragma unroll
        for (int j = 0; j < FN; ++j) acc[i][j] = (f32x4)0.0f;

    for (int k0 = 0; k0 < K; k0 += 64) {
        __syncthreads();
#pragma unroll
        for (int i = 0; i < BM / 32; ++i) {
            int id = i * 256 + t;
            int row = id >> 3, ch = id & 7;
            gld_lds16(&A[(size_t)(m0 + row) * K + k0 + ((ch ^ (row & 7)) * 8)],
                      &As[(size_t)(i * 256 + (t & ~63)) * 8]);
        }
#pragma unroll
        for (int i = 0; i < BN / 32; ++i) {
            int id = i * 256 + t;
            int row = id >> 3, ch = id & 7;
            gld_lds16(&Bt[(size_t)(n0 + row) * K + k0 + ((ch ^ (row & 7)) * 8)],
                      &Bs[(size_t)(i * 256 + (t & ~63)) * 8]);
        }
        __syncthreads();

        short8 af[FM][2], bfr[FN][2];
#pragma unroll
        for (int mi = 0; mi < FM; ++mi) {
            int row = wr * WM + mi * 16 + lr;
#pragma unroll
            for (int ks = 0; ks < 2; ++ks) {
                int ch = (ks * 4 + g) ^ (row & 7);
                af[mi][ks] = *(const short8*)&As[row * 64 + ch * 8];
            }
        }
#pragma unroll
        for (int ni = 0; ni < FN; ++ni) {
            int row = wc * WN + ni * 16 + lr;
#pragma unroll
            for (int ks = 0; ks < 2; ++ks) {
                int ch = (ks * 4 + g) ^ (row & 7);
                bfr[ni][ks] = *(const short8*)&Bs[row * 64 + ch * 8];
            }
        }
#pragma unroll
        for (int ks = 0; ks < 2; ++ks)
#pragma unroll
            for (int mi = 0; mi < FM; ++mi)
#pragma unroll
                for (int ni = 0; ni < FN; ++ni)
                    acc[mi][ni] = __builtin_amdgcn_mfma_f32_16x16x32_bf16(af[mi][ks], bfr[ni][ks], acc[mi][ni], 0, 0, 0);
    }

    const int lg = g;
#pragma unroll
    for (int ni = 0; ni < FN; ++ni) {
        int col = n0 + wc * WN + ni * 16 + lr;
        float bv = bias[col];
#pragma unroll
        for (int mi = 0; mi < FM; ++mi) {
            int row0 = m0 + wr * WM + mi * 16 + lg * 4;
#pragma unroll
            for (int i = 0; i < 4; ++i) {
                int row = row0 + i;
                float x = acc[mi][ni][i] + bv;
                if (RES) x += res[(size_t)row * N + col];
                if (RELU) x = fmaxf(x, 0.0f);
                if (OUT_BF16)
                    ((unsigned short*)C_v)[(size_t)row * N + col] = f2b(x);
                else
                    ((float*)C_v)[(size_t)row * N + col] = x;
            }
        }
    }
}

// ---------------- MFMA flash attention v3: reg-staged K/V + T14 async-split ----------------
// grid (bh=64, qblk=16): XCD locality on bh. Per tile: write staged regs->LDS, barrier,
// ISSUE next tile's global loads to regs (latency hides under compute), then QK/softmax/PV.
// exp2-domain softmax with defer-max (THR = 8*log2e).
__global__ __launch_bounds__(256) void attn_mfma3(const unsigned short* __restrict__ p,
                                                  const unsigned short* __restrict__ pT,
                                                  unsigned short* __restrict__ out) {
    __shared__ __align__(16) unsigned short Ks[64 * 64];
    __shared__ __align__(16) unsigned short Vt[64 * 64];
    __shared__ __align__(16) unsigned short Ps[4 * 16 * 64];

    const int t = threadIdx.x;
    const int lane = t & 63, w = t >> 6;
    const int lr = lane & 15, g = lane >> 4;
    const int bh = blockIdx.x;     // 0..63; consecutive blocks same XCD group
    const int qblk = blockIdx.y;   // 0..15
    const int b = bh >> 4, h = bh & 15;

    const unsigned short* Pm = p + (size_t)b * (1024 * 1024) + h * 64;
    const unsigned short* PT = pT + (size_t)b * (1024 * 1024) + (size_t)(h * 64) * 1024;

    const int q0 = qblk * 64 + w * 16;
    short8 qa0 = *(const short8*)&Pm[(size_t)(q0 + lr) * 1024 + g * 8];
    short8 qa1 = *(const short8*)&Pm[(size_t)(q0 + lr) * 1024 + 32 + g * 8];

    f32x4 acc[4];
#pragma unroll
    for (int i = 0; i < 4; ++i) acc[i] = (f32x4)0.0f;
    float mrow[4] = {-1e30f, -1e30f, -1e30f, -1e30f};
    float lsum[4] = {0.f, 0.f, 0.f, 0.f};

    unsigned short* Pw = &Ps[w * 16 * 64];
    const float C2 = 0.18033688011112042f;   // 0.125 * log2(e)
    const float THR2 = 11.541560327111708f;  // 8 * log2(e)

    // stage registers for one 64x64 K tile + 64x64 V^T tile
    short8 kreg[2], vreg[2];
    const int srow0 = t >> 3, sch0 = t & 7;            // i=0: rows 0..31
    const int srow1 = (256 + t) >> 3, sch1 = t & 7;    // i=1: rows 32..63

#define LOADT(kt)                                                                        \
    {                                                                                    \
        const int key0 = (kt) * 64;                                                      \
        kreg[0] = *(const short8*)&Pm[(size_t)(key0 + srow0) * 1024 + sch0 * 8];         \
        vreg[0] = *(const short8*)&PT[(size_t)srow0 * 1024 + key0 + sch0 * 8];           \
        kreg[1] = *(const short8*)&Pm[(size_t)(key0 + srow1) * 1024 + sch1 * 8];         \
        vreg[1] = *(const short8*)&PT[(size_t)srow1 * 1024 + key0 + sch1 * 8];           \
    }

    LOADT(0);

    for (int kt = 0; kt < 16; ++kt) {
        __syncthreads();  // prev-iter LDS reads complete before overwrite
        {
            int sw0 = (sch0 ^ (srow0 & 7)) * 8;
            int sw1 = (sch1 ^ (srow1 & 7)) * 8;
            *(short8*)&Ks[srow0 * 64 + sw0] = kreg[0];
            *(short8*)&Vt[srow0 * 64 + sw0] = vreg[0];
            *(short8*)&Ks[srow1 * 64 + sw1] = kreg[1];
            *(short8*)&Vt[srow1 * 64 + sw1] = vreg[1];
        }
        __syncthreads();
        if (kt < 15) LOADT(kt + 1);  // issue now; waited at next iter's stage-write

        // QK^T
        f32x4 s_acc[4];
        __builtin_amdgcn_s_setprio(1);
#pragma unroll
        for (int kg = 0; kg < 4; ++kg) {
            s_acc[kg] = (f32x4)0.0f;
            int krow = kg * 16 + lr;
            int swz = (krow & 7) << 3;
            short8 kb0 = *(const short8*)&Ks[krow * 64 + ((g * 8) ^ swz)];
            short8 kb1 = *(const short8*)&Ks[krow * 64 + ((32 + g * 8) ^ swz)];
            s_acc[kg] = __builtin_amdgcn_mfma_f32_16x16x32_bf16(qa0, kb0, s_acc[kg], 0, 0, 0);
            s_acc[kg] = __builtin_amdgcn_mfma_f32_16x16x32_bf16(qa1, kb1, s_acc[kg], 0, 0, 0);
        }
        __builtin_amdgcn_s_setprio(0);

        // scale to base-2 domain: t = s * 0.125 * log2e
#pragma unroll
        for (int kg = 0; kg < 4; ++kg)
#pragma unroll
            for (int reg = 0; reg < 4; ++reg) s_acc[kg][reg] *= C2;

        float mx[4];
#pragma unroll
        for (int reg = 0; reg < 4; ++reg) {
            float m = fmaxf(fmaxf(s_acc[0][reg], s_acc[1][reg]),
                            fmaxf(s_acc[2][reg], s_acc[3][reg]));
            m = fmaxf(m, __shfl_xor(m, 1));
            m = fmaxf(m, __shfl_xor(m, 2));
            m = fmaxf(m, __shfl_xor(m, 4));
            m = fmaxf(m, __shfl_xor(m, 8));
            mx[reg] = m;
        }
        bool small = (mx[0] <= mrow[0] + THR2) && (mx[1] <= mrow[1] + THR2) &&
                     (mx[2] <= mrow[2] + THR2) && (mx[3] <= mrow[3] + THR2);
        if (__all(small)) {
#pragma unroll
            for (int reg = 0; reg < 4; ++reg) {
                float psum = 0.f;
#pragma unroll
                for (int kg = 0; kg < 4; ++kg) {
                    float pv = fast_exp2(s_acc[kg][reg] - mrow[reg]);
                    s_acc[kg][reg] = pv;
                    psum += pv;
                }
                psum += __shfl_xor(psum, 1);
                psum += __shfl_xor(psum, 2);
                psum += __shfl_xor(psum, 4);
                psum += __shfl_xor(psum, 8);
                lsum[reg] += psum;
            }
        } else {
#pragma unroll
            for (int reg = 0; reg < 4; ++reg) {
                float mnew = fmaxf(mrow[reg], mx[reg]);
                float scale = fast_exp2(mrow[reg] - mnew);
                mrow[reg] = mnew;
                float psum = 0.f;
#pragma unroll
                for (int kg = 0; kg < 4; ++kg) {
                    float pv = fast_exp2(s_acc[kg][reg] - mnew);
                    s_acc[kg][reg] = pv;
                    psum += pv;
                }
                psum += __shfl_xor(psum, 1);
                psum += __shfl_xor(psum, 2);
                psum += __shfl_xor(psum, 4);
                psum += __shfl_xor(psum, 8);
                lsum[reg] = lsum[reg] * scale + psum;
#pragma unroll
                for (int dg = 0; dg < 4; ++dg) acc[dg][reg] *= scale;
            }
        }

        // P (C-layout) -> per-wave LDS -> A-frag layout
#pragma unroll
        for (int reg = 0; reg < 4; ++reg) {
            int q = g * 4 + reg;
            int swz = (q & 7) << 3;
#pragma unroll
            for (int kg = 0; kg < 4; ++kg) {
                int key = lr + 16 * kg;
                Pw[q * 64 + (key ^ swz)] = f2b(s_acc[kg][reg]);
            }
        }
        int pswz = (lr & 7) << 3;
        short8 pa0 = *(const short8*)&Pw[lr * 64 + ((g * 8) ^ pswz)];
        short8 pa1 = *(const short8*)&Pw[lr * 64 + ((32 + g * 8) ^ pswz)];

        // PV
        __builtin_amdgcn_s_setprio(1);
#pragma unroll
        for (int dg = 0; dg < 4; ++dg) {
            int drow = dg * 16 + lr;
            int swz = (drow & 7) << 3;
            short8 vb0 = *(const short8*)&Vt[drow * 64 + ((g * 8) ^ swz)];
            short8 vb1 = *(const short8*)&Vt[drow * 64 + ((32 + g * 8) ^ swz)];
            acc[dg] = __builtin_amdgcn_mfma_f32_16x16x32_bf16(pa0, vb0, acc[dg], 0, 0, 0);
            acc[dg] = __builtin_amdgcn_mfma_f32_16x16x32_bf16(pa1, vb1, acc[dg], 0, 0, 0);
        }
        __builtin_amdgcn_s_setprio(0);
    }
#undef LOADT

    unsigned short* O = out + (size_t)b * (1024 * 1024) + h * 64;
#pragma unroll
    for (int reg = 0; reg < 4; ++reg) {
        float inv = 1.0f / lsum[reg];
        int q = q0 + g * 4 + reg;
#pragma unroll
        for (int dg = 0; dg < 4; ++dg) {
            O[(size_t)q * 1024 + dg * 16 + lr] = f2b(acc[dg][reg] * inv);
        }
    }
}

// ---------------- launch ----------------
extern "C" void kernel_launch(void* const* d_in, const int* in_sizes, int n_in,
                              void* d_out, int out_size, void* d_ws, size_t ws_size,
                              hipStream_t stream) {
    const float* x = (const float*)d_in[0];
    const float* wq_w = (const float*)d_in[1];
    const float* wq_b = (const float*)d_in[2];
    const float* wo_w = (const float*)d_in[3];
    const float* wo_b = (const float*)d_in[4];
    const float* ff1_w = (const float*)d_in[5];
    const float* ff1_b = (const float*)d_in[6];
    const float* ff2_w = (const float*)d_in[7];
    const float* ff2_b = (const float*)d_in[8];
    const float* alpha1 = (const float*)d_in[9];
    const float* bias1 = (const float*)d_in[10];
    const float* alpha2 = (const float*)d_in[11];
    const float* bias2 = (const float*)d_in[12];
    const float* alpha3 = (const float*)d_in[13];
    const float* bias3 = (const float*)d_in[14];
    float* out = (float*)d_out;

    const size_t MB = 1u << 20;
    char* ws = (char*)d_ws;
    unsigned short* wq_t = (unsigned short*)(ws + 0 * MB);
    unsigned short* wo_t = (unsigned short*)(ws + 2 * MB);
    unsigned short* ff1_t = (unsigned short*)(ws + 4 * MB);
    unsigned short* ff2_t = (unsigned short*)(ws + 12 * MB);
    unsigned short* lnbuf = (unsigned short*)(ws + 20 * MB);
    unsigned short* pbuf = (unsigned short*)(ws + 28 * MB);
    unsigned short* attn = (unsigned short*)(ws + 36 * MB);
    float* h1 = (float*)(ws + 44 * MB);
    unsigned short* pbT = (unsigned short*)(ws + 60 * MB);
    unsigned short* mid = (unsigned short*)(ws + 60 * MB);
    float* h2 = (float*)(ws + 28 * MB);

    const int M = 4096;

    transpose_cast_kernel<<<dim3(32, 32), dim3(32, 8), 0, stream>>>(wq_w, wq_t, 1024, 1024);
    transpose_cast_kernel<<<dim3(32, 32), dim3(32, 8), 0, stream>>>(wo_w, wo_t, 1024, 1024);
    transpose_cast_kernel<<<dim3(128, 32), dim3(32, 8), 0, stream>>>(ff1_w, ff1_t, 1024, 4096);
    transpose_cast_kernel<<<dim3(32, 128), dim3(32, 8), 0, stream>>>(ff2_w, ff2_t, 4096, 1024);

    ln_kernel<true><<<M, 256, 0, stream>>>(x, lnbuf, alpha1, bias1);
    gemm2<128, 64, false, false, true><<<512, 256, 0, stream>>>(lnbuf, wq_t, wq_b, nullptr, pbuf, M, 1024, 1024);
    transpose_bf16_batch<<<dim3(32, 32, 4), dim3(32, 8), 0, stream>>>(pbuf, pbT);
    attn_mfma3<<<dim3(64, 16), 256, 0, stream>>>(pbuf, pbT, attn);
    gemm2<128, 64, false, true, false><<<512, 256, 0, stream>>>(attn, wo_t, wo_b, x, h1, M, 1024, 1024);
    ln_kernel<true><<<M, 256, 0, stream>>>(h1, lnbuf, alpha2, bias2);
    gemm2<128, 128, true, false, true><<<1024, 256, 0, stream>>>(lnbuf, ff1_t, ff1_b, nullptr, mid, M, 4096, 1024);
    gemm2<128, 64, false, true, false><<<512, 256, 0, stream>>>(mid, ff2_t, ff2_b, h1, h2, M, 1024, 4096);
    ln_kernel<false><<<M, 256, 0, stream>>>(h2, out, alpha3, bias3);
}